// Round 5
// baseline (359.397 us; speedup 1.0000x reference)
//
#include <hip/hip_runtime.h>

// LSTM B=8192, T=512, I=1, H=32; out[b] = h_T . W_lin + b_lin.  All I/O f32.
//
// R18: lane-local recurrence + MFMA C-init (R17) + STAGED WIDTH-8 ACTS.
// R17 post-mortem: VGPR_Count stayed 132 after deleting 64 regs of consts
// -> registers never constrained; the compiler emitted the 4 ACT_PAIR
// blocks as 4 SERIAL ~150-200cyc dependent chains (minimal-liveness
// schedule), and at 0.5 wave/SIMD nothing fills the bubbles: wall 1417 vs
// static issue ~450-650. Fix: restructure the acts as width-8 stages (all
// 32 exp2, then all adds, then 8 tIG, ... then 4 pkrtz) so PROGRAM ORDER
// carries the ILP; op set / operand order / pairing bit-identical to the
// verified ACT_PAIR math (absmax must stay 9.77e-4). ds_read of x[t+1]
// hoisted to loop top. Discriminator: wall ~500-750 -> ~110-160us (line
// lives); wall >=1300 -> SIMD trans throughput is the wall, lane-local is
// structurally dead -> terminal answer is the R13 4-wave kernel (171us).
// NOTE: packed f32x2 (v_pk_*) acts failed post-timing determinism in R12 -
// do not reintroduce.
//
// Ledger (dur_us): dot2-VALU 490 -> mfma 1-wave 360 -> 2-wave 297 -> 4-wave
// trans-split 215 -> 8-wave custom 190 -> 4-wave custom 171/179 -> R15
// dual-wave-group 240 (FAILED: wall=P+I) -> R16 lane-local 313 (serial act
// chains) -> R17 +MFMA-C-init 302 (regs not the fix; serial chains remain)
// -> this.

#define L2E 1.4426950408889634f

typedef _Float16 f16x8 __attribute__((ext_vector_type(8)));
typedef float    f32x4 __attribute__((ext_vector_type(4)));

__global__ __launch_bounds__(64, 1) void lstm_lls(
    const float* __restrict__ x,      // [B*512]
    const float* __restrict__ W_ih,   // [128]
    const float* __restrict__ W_hh,   // [128*32]
    const float* __restrict__ b_ih,   // [128]
    const float* __restrict__ b_hh,   // [128]
    const float* __restrict__ W_lin,  // [32]
    const float* __restrict__ b_lin,  // [1]
    float* __restrict__ out)          // [B]
{
    __shared__ float xs[512 * 17];     // x transposed [t][b], stride 17 (34.8 KB)

    const int tid  = threadIdx.x;      // one wave per block
    const int col  = tid & 15;         // batch within group
    const int quad = tid >> 4;         // 0..3: owns hiddens [8quad, 8quad+8)
    const int base = blockIdx.x * 16;  // global batch base

    // ---- stage x[base..base+15][0..511] into LDS transposed ----
    {
        const float4* xg = (const float4*)(x + (size_t)base * 512);
        #pragma unroll 4
        for (int i = 0; i < 32; ++i) {
            int idx = i * 64 + tid;            // 0..2047 float4s
            int b   = idx >> 7;                // batch 0..15
            int tq  = idx & 127;               // float4 within batch row
            float4 v = xg[b * 128 + tq];
            int t0 = tq * 4;
            xs[(t0 + 0) * 17 + b] = v.x;
            xs[(t0 + 1) * 17 + b] = v.y;
            xs[(t0 + 2) * 17 + b] = v.z;
            xs[(t0 + 3) * 17 + b] = v.w;
        }
    }

    // ---- main A-tiles: MFMA m, A-row rho=4a+r -> W_hh gate-row 32r+8a+m.
    // Lane(quad,col) acc[m] slot r = gate r of hidden 8quad+m, batch col. ----
    f16x8 wA[8];
    {
        const int r = col & 3;
        const int a = col >> 2;
        const float s = (r == 2) ? (2.0f * L2E) : L2E;
        #pragma unroll
        for (int m = 0; m < 8; ++m) {
            const int grow = 32 * r + 8 * a + m;
            #pragma unroll
            for (int j = 0; j < 8; ++j)
                wA[m][j] = (_Float16)(W_hh[grow * 32 + quad * 8 + j] * s);
        }
    }

    // ---- bias A2-tiles (C-init MFMA, R17-verified): k rows 0..4 =
    // wih_hi, wih_hi, wih_lo, bia_hi, bia_lo (only quad-0 lanes nonzero). ----
    f16x8 wA2[8];
    #pragma unroll
    for (int m = 0; m < 8; ++m) wA2[m] = (f16x8){};
    if (quad == 0) {
        const int r = col & 3;
        const int a = col >> 2;
        const float s = (r == 2) ? (2.0f * L2E) : L2E;
        #pragma unroll
        for (int m = 0; m < 8; ++m) {
            const int g = 32 * r + 8 * a + m;
            const float wih = W_ih[g] * s;
            const float bia = (b_ih[g] + b_hh[g]) * s;
            _Float16 wh = (_Float16)wih;
            _Float16 wl = (_Float16)(wih - (float)wh);
            _Float16 bh = (_Float16)bia;
            _Float16 bl = (_Float16)(bia - (float)bh);
            wA2[m][0] = wh; wA2[m][1] = wh; wA2[m][2] = wl;
            wA2[m][3] = bh; wA2[m][4] = bl;
        }
    }

    __syncthreads();

    const f32x4 fzero = {0.f, 0.f, 0.f, 0.f};
    float cc[8] = {0.f, 0.f, 0.f, 0.f, 0.f, 0.f, 0.f, 0.f};
    float hl[8];
    f16x8 bfrag = {};                  // h = 0
    f32x4 cq[8];
    {
        // t=0 C-init via bias-MFMA: B rows k=0..4 = (x_hi, x_lo, x_hi, 1, 1)
        float xt = xs[col];
        _Float16 xh16 = (_Float16)xt;
        _Float16 xl16 = (_Float16)(xt - (float)xh16);
        f16x8 b2 = {};
        b2[0] = xh16; b2[1] = xl16; b2[2] = xh16;
        b2[3] = (_Float16)1.0f; b2[4] = (_Float16)1.0f;
        #pragma unroll
        for (int m = 0; m < 8; ++m)
            cq[m] = __builtin_amdgcn_mfma_f32_16x16x32_f16(wA2[m], b2, fzero, 0, 0, 0);
    }

    for (int t = 0; t < 512; ++t) {
        float xt1 = xs[((t + 1) & 511) * 17 + col];   // ds_read early; used only at b2 build

        f32x4 acc[8];
        #pragma unroll
        for (int m = 0; m < 8; ++m)
            acc[m] = __builtin_amdgcn_mfma_f32_16x16x32_f16(wA[m], bfrag, cq[m], 0, 0, 0);

        // ---- staged activations, width 8 (op-identical to verified ACT_PAIR) ----
        float eI[8], eF[8], eG[8], eO[8];
        #pragma unroll
        for (int m = 0; m < 8; ++m) {
            eI[m] = __builtin_amdgcn_exp2f(-acc[m][0]);
            eF[m] = __builtin_amdgcn_exp2f(-acc[m][1]);
            eG[m] = __builtin_amdgcn_exp2f(-acc[m][2]);
            eO[m] = __builtin_amdgcn_exp2f(-acc[m][3]);
        }
        float aI[8], aF[8], aG[8], aO[8], gm1[8];
        #pragma unroll
        for (int m = 0; m < 8; ++m) {
            aI[m] = 1.0f + eI[m];
            aF[m] = 1.0f + eF[m];
            aG[m] = 1.0f + eG[m];
            aO[m] = 1.0f + eO[m];
            gm1[m] = 1.0f - eG[m];
        }
        float tIG[8], num[8], D[8];
        #pragma unroll
        for (int m = 0; m < 8; ++m) {
            tIG[m] = aI[m] * aG[m];
            num[m] = fmaf(cc[m], tIG[m], gm1[m] * aF[m]);
            D[m]   = aF[m] * tIG[m];
        }
        float rD[4];
        #pragma unroll
        for (int p = 0; p < 4; ++p)
            rD[p] = __builtin_amdgcn_rcpf(D[2 * p] * D[2 * p + 1]);
        #pragma unroll
        for (int p = 0; p < 4; ++p) {
            cc[2 * p]     = num[2 * p]     * (rD[p] * D[2 * p + 1]);
            cc[2 * p + 1] = num[2 * p + 1] * (rD[p] * D[2 * p]);
        }
        float ec[8];
        #pragma unroll
        for (int m = 0; m < 8; ++m)
            ec[m] = __builtin_amdgcn_exp2f(cc[m] * (-2.0f * L2E));
        float Hq[8];
        #pragma unroll
        for (int m = 0; m < 8; ++m)
            Hq[m] = aO[m] * (1.0f + ec[m]);
        float rH[4];
        #pragma unroll
        for (int p = 0; p < 4; ++p)
            rH[p] = __builtin_amdgcn_rcpf(Hq[2 * p] * Hq[2 * p + 1]);
        #pragma unroll
        for (int p = 0; p < 4; ++p) {
            hl[2 * p]     = (1.0f - ec[2 * p])     * (rH[p] * Hq[2 * p + 1]);
            hl[2 * p + 1] = (1.0f - ec[2 * p + 1]) * (rH[p] * Hq[2 * p]);
        }

        // lane-local B-frag: slot j = h of hidden 8quad+j
        union { f16x8 v; unsigned int u[4]; } bb;
        #pragma unroll
        for (int p = 0; p < 4; ++p)
            bb.u[p] = __builtin_bit_cast(unsigned int,
                        __builtin_amdgcn_cvt_pkrtz(hl[2 * p], hl[2 * p + 1]));
        bfrag = bb.v;

        // next step's C-init on the matrix pipe (result needed only next iter)
        {
            _Float16 xh16 = (_Float16)xt1;
            _Float16 xl16 = (_Float16)(xt1 - (float)xh16);
            f16x8 b2 = {};
            b2[0] = xh16; b2[1] = xl16; b2[2] = xh16;
            b2[3] = (_Float16)1.0f; b2[4] = (_Float16)1.0f;
            #pragma unroll
            for (int m = 0; m < 8; ++m)
                cq[m] = __builtin_amdgcn_mfma_f32_16x16x32_f16(wA2[m], b2, fzero, 0, 0, 0);
        }
    }

    // ---- epilogue: out[b] = sum_j h_j * W_lin[j] + b_lin ----
    float v = 0.0f;
    #pragma unroll
    for (int j = 0; j < 8; ++j)
        v = fmaf(hl[j], W_lin[8 * quad + j], v);
    v += __shfl_xor(v, 16);            // combine quads
    v += __shfl_xor(v, 32);
    if (tid < 16)
        out[base + col] = v + b_lin[0];
}

extern "C" void kernel_launch(void* const* d_in, const int* in_sizes, int n_in,
                              void* d_out, int out_size, void* d_ws, size_t ws_size,
                              hipStream_t stream) {
    const float* x     = (const float*)d_in[0];
    const float* W_ih  = (const float*)d_in[1];
    const float* W_hh  = (const float*)d_in[2];
    const float* b_ih  = (const float*)d_in[3];
    const float* b_hh  = (const float*)d_in[4];
    const float* W_lin = (const float*)d_in[5];
    const float* b_lin = (const float*)d_in[6];
    float* out = (float*)d_out;

    const int B = in_sizes[0] / 512;   // 8192
    dim3 grid(B / 16), block(64);
    lstm_lls<<<grid, block, 0, stream>>>(x, W_ih, W_hh, b_ih, b_hh, W_lin, b_lin, out);
}

// Round 6
// 259.567 us; speedup vs baseline: 1.3846x; 1.3846x over previous
//
#include <hip/hip_runtime.h>

// LSTM B=8192, T=512, I=1, H=32; out[b] = h_T . W_lin + b_lin.  All I/O f32.
//
// R19: 8-batch groups, 2 waves/block, 1024 blocks = 4 independent blocks/CU.
// Session model (fits R13=801, R15=1125, R16/18=~1460 cyc/step): wave64
// trans op = ~16 cyc issue; per-CU-step trans floor = 384 cyc/SIMD when all
// SIMDs evenly loaded; R13 wall = P(~530: barrier+ds_read130+mfma+act chain)
// + I(273), with only ONE co-resident wave (2 blocks/CU) to cover P.
// Fix: shrink group to 8 batches so 1024 independent blocks give 4 block
// phases/CU; their drift covers P. Wave owns 16 hiddens via 4 custom-tile
// MFMAs; B-frag cols 8..15 MIRROR batches 0..7, lane(q,col>=8) SELECTS
// MFMAs {2,3} vs {0,1} (8 cndmask) -> still 2 instances/lane, 12 trans/wave
// -> 384 cyc/SIMD at 2 waves/SIMD (floor preserved, no duplication).
// Wall pred: max(2*I, P+I-cover) ~600-660 -> ~135-150us rocprof.
// ACT math identical to R13 (paired rcp, pkrtz; absmax must stay 9.77e-4).
// NOTE: packed f32x2 (v_pk_*) acts failed post-timing determinism in R12.
//
// Ledger (rocprof us): R13 4-wave custom 179 -> R15 dual-group 240 (FAILED
// wall=P+I) -> R16 lane-local 313 / R17 +mfma-cinit 302 / R18 staged 312
// (FAILED: 48 trans on 1 SIMD = 768cyc floor, 2 SIMDs idle) -> this.
// If >=179: structure converged, R13 is terminal.

#define L2E 1.4426950408889634f

typedef _Float16 f16x8 __attribute__((ext_vector_type(8)));
typedef float    f32x4 __attribute__((ext_vector_type(4)));

__global__ __launch_bounds__(128, 2) void lstm_g8(
    const float* __restrict__ x,      // [B*512]
    const float* __restrict__ W_ih,   // [128]
    const float* __restrict__ W_hh,   // [128*32]
    const float* __restrict__ b_ih,   // [128]
    const float* __restrict__ b_hh,   // [128]
    const float* __restrict__ W_lin,  // [32]
    const float* __restrict__ b_lin,  // [1]
    float* __restrict__ out)          // [B]
{
    __shared__ float xs[512 * 9];                        // x transposed [t][b], stride 9 (18.4 KB)
    __shared__ __align__(16) unsigned int hb[2][8 * 20]; // h half2, row/batch stride 20 dwords
    __shared__ float ps[16];                             // epilogue partials

    const int tid  = threadIdx.x;
    const int wv   = tid >> 6;         // 0/1: owns hiddens [16wv, 16wv+16)
    const int lane = tid & 63;
    const int col  = lane & 15;        // MFMA column
    const int b    = col & 7;          // batch within group (cols 8..15 mirror)
    const int hi   = col >> 3;         // 0: MFMAs {0,1}; 1: MFMAs {2,3}
    const int quad = lane >> 4;        // 0..3
    const int base = blockIdx.x * 8;   // global batch base

    // ---- stage x[base..base+7][0..511] into LDS transposed ----
    {
        const float* gx = x + (size_t)base * 512;
        #pragma unroll
        for (int i = 0; i < 8; ++i) {
            int bb = i;                        // batch row this iter
            float4 v = ((const float4*)(gx + (size_t)bb * 512))[tid];
            int t0 = tid * 4;
            xs[(t0 + 0) * 9 + bb] = v.x;
            xs[(t0 + 1) * 9 + bb] = v.y;
            xs[(t0 + 2) * 9 + bb] = v.z;
            xs[(t0 + 3) * 9 + bb] = v.w;
        }
    }

    // ---- custom A-tiles: MFMA n (0..3): A-row rho=4a+r -> W_hh gate-row
    // [32r + 16wv + 4a + n].  Lane(q,col) acc_n slot r = gate r of hidden
    // 16wv+4q+n, batch col&7 (cols mirror).  A-frag: row=col, k=8q+j. ----
    f16x8 wA[4];
    {
        const int r = col & 3;
        const int a = col >> 2;
        const float s = (r == 2) ? (2.0f * L2E) : L2E;
        #pragma unroll
        for (int n = 0; n < 4; ++n) {
            const int grow = 32 * r + 16 * wv + 4 * a + n;
            #pragma unroll
            for (int j = 0; j < 8; ++j)
                wA[n][j] = (_Float16)(W_hh[grow * 32 + 8 * quad + j] * s);
        }
    }

    // lane's two hiddens: j0 = 16wv + 4q + 2*hi, j0+1
    const int j0 = 16 * wv + 4 * quad + 2 * hi;
    float wih[2][4], bia[2][4];
    #pragma unroll
    for (int p = 0; p < 2; ++p)
        #pragma unroll
        for (int r = 0; r < 4; ++r) {
            const float s = (r == 2) ? (2.0f * L2E) : L2E;
            const int g = 32 * r + j0 + p;
            wih[p][r] = W_ih[g] * s;
            bia[p][r] = (b_ih[g] + b_hh[g]) * s;
        }
    const float wl0 = W_lin[j0], wl1 = W_lin[j0 + 1];

    __syncthreads();

    float c0 = 0.0f, c1 = 0.0f, h0 = 0.0f, h1 = 0.0f;
    f16x8 bfrag = {};                  // h = 0
    f32x4 cq[2];
    {
        float xt = xs[b];              // t = 0
        #pragma unroll
        for (int p = 0; p < 2; ++p)
            #pragma unroll
            for (int r = 0; r < 4; ++r)
                cq[p][r] = fmaf(xt, wih[p][r], bia[p][r]);
    }

    // h-pair write dword: batch row b, pair index 8wv+2q+hi
    const int wr = b * 20 + 8 * wv + 2 * quad + hi;
    // B-frag read dword: batch row b, dwords 4q..4q+3 (hiddens 8q..8q+7)
    const int rd = b * 20 + 4 * quad;

    #pragma unroll 4
    for (int t = 0; t < 512; ++t) {
        unsigned int* buf = hb[t & 1];

        // 4 MFMAs: acc_n = gates of hidden 16wv+4q+n (cols mirror batches)
        f32x4 a0 = __builtin_amdgcn_mfma_f32_16x16x32_f16(wA[0], bfrag, cq[0], 0, 0, 0);
        f32x4 a1 = __builtin_amdgcn_mfma_f32_16x16x32_f16(wA[1], bfrag, cq[1], 0, 0, 0);
        f32x4 a2 = __builtin_amdgcn_mfma_f32_16x16x32_f16(wA[2], bfrag, cq[0], 0, 0, 0);
        f32x4 a3 = __builtin_amdgcn_mfma_f32_16x16x32_f16(wA[3], bfrag, cq[1], 0, 0, 0);

        float xt1 = xs[((t + 1) & 511) * 9 + b];          // prefetch next x

        // col-half select: this lane activates hiddens j0, j0+1
        f32x4 s0, s1;
        #pragma unroll
        for (int r = 0; r < 4; ++r) {
            s0[r] = hi ? a2[r] : a0[r];
            s1[r] = hi ? a3[r] : a1[r];
        }

        // fused activations (R13-verified), hiddens j0 (s0), j0+1 (s1); rcps PAIRED
        float ei0 = __builtin_amdgcn_exp2f(-s0[0]);
        float ef0 = __builtin_amdgcn_exp2f(-s0[1]);
        float eg0 = __builtin_amdgcn_exp2f(-s0[2]);
        float eo0 = __builtin_amdgcn_exp2f(-s0[3]);
        float ei1 = __builtin_amdgcn_exp2f(-s1[0]);
        float ef1 = __builtin_amdgcn_exp2f(-s1[1]);
        float eg1 = __builtin_amdgcn_exp2f(-s1[2]);
        float eo1 = __builtin_amdgcn_exp2f(-s1[3]);
        float aI0 = 1.0f + ei0, aF0 = 1.0f + ef0, aG0 = 1.0f + eg0, aO0 = 1.0f + eo0;
        float aI1 = 1.0f + ei1, aF1 = 1.0f + ef1, aG1 = 1.0f + eg1, aO1 = 1.0f + eo1;
        float tIG0 = aI0 * aG0, tIG1 = aI1 * aG1;
        float num0 = fmaf(c0, tIG0, (1.0f - eg0) * aF0);
        float num1 = fmaf(c1, tIG1, (1.0f - eg1) * aF1);
        float D0 = aF0 * tIG0, D1 = aF1 * tIG1;
        float rD = __builtin_amdgcn_rcpf(D0 * D1);        // paired rcp #1
        c0 = num0 * (rD * D1);
        c1 = num1 * (rD * D0);
        float ec0 = __builtin_amdgcn_exp2f(c0 * (-2.0f * L2E));
        float ec1 = __builtin_amdgcn_exp2f(c1 * (-2.0f * L2E));
        float H0 = aO0 * (1.0f + ec0), H1 = aO1 * (1.0f + ec1);
        float rH = __builtin_amdgcn_rcpf(H0 * H1);        // paired rcp #2
        h0 = (1.0f - ec0) * (rH * H1);
        h1 = (1.0f - ec1) * (rH * H0);

        // adjacent hiddens -> one b32 write of the packed pair
        buf[wr] = __builtin_bit_cast(unsigned int, __builtin_amdgcn_cvt_pkrtz(h0, h1));

        // next step's C-init in the pre-barrier slack
        #pragma unroll
        for (int p = 0; p < 2; ++p)
            #pragma unroll
            for (int r = 0; r < 4; ++r)
                cq[p][r] = fmaf(xt1, wih[p][r], bia[p][r]);

        __syncthreads();
        // B-frag: hiddens 8q..8q+7 of batch b (cols 8..15 mirror: broadcast)
        uint4 bv = *(const uint4*)&buf[rd];
        bfrag = __builtin_bit_cast(f16x8, bv);
    }

    // ---- epilogue: out[b] = sum_j h_j * W_lin[j] + b_lin ----
    float v = fmaf(h0, wl0, h1 * wl1);
    v += __shfl_xor(v, 8);             // combine col-halves (hiddens +2,+3)
    v += __shfl_xor(v, 16);            // combine quads
    v += __shfl_xor(v, 32);
    if (lane < 8) ps[wv * 8 + lane] = v;
    __syncthreads();
    if (tid < 8)
        out[base + tid] = b_lin[0] + ps[tid] + ps[8 + tid];
}

extern "C" void kernel_launch(void* const* d_in, const int* in_sizes, int n_in,
                              void* d_out, int out_size, void* d_ws, size_t ws_size,
                              hipStream_t stream) {
    const float* x     = (const float*)d_in[0];
    const float* W_ih  = (const float*)d_in[1];
    const float* W_hh  = (const float*)d_in[2];
    const float* b_ih  = (const float*)d_in[3];
    const float* b_hh  = (const float*)d_in[4];
    const float* W_lin = (const float*)d_in[5];
    const float* b_lin = (const float*)d_in[6];
    float* out = (float*)d_out;

    const int B = in_sizes[0] / 512;   // 8192
    dim3 grid(B / 8), block(128);
    lstm_g8<<<grid, block, 0, stream>>>(x, W_ih, W_hh, b_ih, b_hh, W_lin, b_lin, out);
}

// Round 7
// 195.816 us; speedup vs baseline: 1.8354x; 1.3256x over previous
//
#include <hip/hip_runtime.h>

// LSTM B=8192, T=512, I=1, H=32; out[b] = h_T . W_lin + b_lin.  All I/O f32.
//
// R20: RESTORE R13 (session-best 171-179us rocprof) + s_setprio(1) around
// the serial act chain (T5; proven regime = co-resident waves from
// different blocks at drifted phases, which is exactly this kernel).
//
// Structure-search verdict (R15-R19, all measured): R13's 4-wave/16-batch
// exchange structure is the family optimum at 801 cyc/step.
//   R15 1-wave/SIMD dual-group: 1125 (wall=P+I; co-wave was free cover)
//   R16/R17/R18 lane-local 1-wave: ~1460 (48 trans/step on ONE SIMD =
//     768cyc floor; trans op ~16 cyc issue; staging/ILP/regs irrelevant)
//   R19 8-batch 2-wave blocks: 1023 (per-wave I up +50, no added cover)
// Model: trans floor 384 cyc/SIMD/step + ~190 busy + ~230 uncovered chain
// = 801. Busy floor ~117us; remaining gap is serial-chain latency that
// 2 waves/SIMD (grid-capped: 512 16-batch groups = 2 blocks/CU) can't
// fully cover. setprio is the last cheap lever on the uncovered term.
//
// MFMA formulation, 4 waves per 16-batch group (512 blocks x 256 threads),
// custom tiles (zero MFMA duplication), 2 hiddens/lane, fused activations
// with PAIRED rcp. Wave wv owns hiddens [8wv, 8wv+8). Lane (quad,col) owns
// j0 = 8wv+2quad+0 and j1 = j0+1 of batch col. Custom A-tile tau: row
// m = 4a+r holds W_hh gate-row [type r][hidden 8wv+2a+tau] (row-permuting A
// permutes D rows identically), so acc[tau] slots 0..3 = {i,f,g,o} of
// hidden j0+tau. 2 MFMAs/wave-step, no duplication. 2048 waves = 2/SIMD.
//
// Activations (12 trans/lane-step = 10 exp2 + 2 paired rcp — the algebraic
// floor of 5 exp2 + ~1 rcp per hidden-step):
//   e* = 2^(-z*'), a* = 1+e*;  D = aF*aI*aG per hidden
//   paired: r = rcp(D0*D1); 1/D0 = r*D1, 1/D1 = r*D0
//   c' = (c*aI*aG + (1-eG)*aF) / D
//   eC = 2^(-2*L2E*c'); H = aO*(1+eC) paired-rcp; h = (1-eC)/H
// Pre-acts pre-scaled by L2E (2*L2E for the g gate).
//
// Ledger (rocprof us/step-cyc): R13 179/801 (THIS) -> R15 240/1125 FAILED
// -> R16 313 / R17 302 / R18 312 (~1460) FAILED -> R19 218/1023 FAILED.
// NOTE: packed f32x2 (v_pk_*) acts failed post-timing determinism in R12 -
// do not reintroduce.

#define L2E 1.4426950408889634f

typedef _Float16 f16x8 __attribute__((ext_vector_type(8)));
typedef float    f32x4 __attribute__((ext_vector_type(4)));

__global__ __launch_bounds__(256, 4) void lstm_ct4r(
    const float* __restrict__ x,      // [B*512]
    const float* __restrict__ W_ih,   // [128]
    const float* __restrict__ W_hh,   // [128*32]
    const float* __restrict__ b_ih,   // [128]
    const float* __restrict__ b_hh,   // [128]
    const float* __restrict__ W_lin,  // [32]
    const float* __restrict__ b_lin,  // [1]
    float* __restrict__ out)          // [B]
{
    __shared__ float xs[512 * 17];                        // x transposed [t][b], stride 17
    __shared__ __align__(16) unsigned int hb[2][16 * 20]; // h half2 buffers, col-stride 20 uints
    __shared__ float ps[64];                              // epilogue partials

    const int tid  = threadIdx.x;
    const int wv   = tid >> 6;         // 0..3: owns hiddens [8wv, 8wv+8)
    const int lane = tid & 63;
    const int col  = lane & 15;        // batch within group
    const int quad = lane >> 4;        // 0..3
    const int base = blockIdx.x * 16;  // global batch base

    // ---- stage x[base..base+15][0..511] into LDS transposed ----
    {
        const float4* xg = (const float4*)(x + (size_t)base * 512);
        #pragma unroll
        for (int it = 0; it < 8; ++it) {
            int idx = it * 256 + tid;          // 0..2047 float4s
            float4 v = xg[idx];
            int b  = idx >> 7;                 // batch 0..15
            int t0 = (idx & 127) * 4;
            xs[(t0 + 0) * 17 + b] = v.x;
            xs[(t0 + 1) * 17 + b] = v.y;
            xs[(t0 + 2) * 17 + b] = v.z;
            xs[(t0 + 3) * 17 + b] = v.w;
        }
    }

    // ---- custom A-tiles: tile tau row m=4a+rt -> W_hh[32*rt + 8wv+2a+tau] ----
    f16x8 wA[2];
    #pragma unroll
    for (int tau = 0; tau < 2; ++tau) {
        const int rt = col & 3;                           // gate type of row col
        const float s = (rt == 2) ? (2.0f * L2E) : L2E;
        const int grow = 32 * rt + 8 * wv + 2 * (col >> 2) + tau;
        #pragma unroll
        for (int j = 0; j < 8; ++j)
            wA[tau][j] = (_Float16)(W_hh[grow * 32 + quad * 8 + j] * s);
    }
    // C-init constants: acc[tau] slot r = gate type r of hidden j0+tau
    const int j0 = 8 * wv + 2 * quad;                     // first owned hidden
    float wih[2][4], bia[2][4];
    #pragma unroll
    for (int tau = 0; tau < 2; ++tau)
        #pragma unroll
        for (int r = 0; r < 4; ++r) {
            const float s = (r == 2) ? (2.0f * L2E) : L2E;
            const int g = 32 * r + j0 + tau;
            wih[tau][r] = W_ih[g] * s;
            bia[tau][r] = (b_ih[g] + b_hh[g]) * s;
        }
    const float wl0 = W_lin[j0], wl1 = W_lin[j0 + 1];

    __syncthreads();

    float c0 = 0.0f, c1 = 0.0f, h0 = 0.0f, h1 = 0.0f;
    f16x8 bfrag = {};                  // h = 0
    f32x4 cq[2];
    {
        float xt = xs[col];            // t = 0
        #pragma unroll
        for (int tau = 0; tau < 2; ++tau)
            #pragma unroll
            for (int r = 0; r < 4; ++r)
                cq[tau][r] = fmaf(xt, wih[tau][r], bia[tau][r]);
    }

    const int wr = col * 20 + 4 * wv + quad;   // h-pair write index (= j0/2 slot)

    #pragma unroll 4
    for (int t = 0; t < 512; ++t) {
        unsigned int* buf = hb[t & 1];

        f32x4 a0 = __builtin_amdgcn_mfma_f32_16x16x32_f16(wA[0], bfrag, cq[0], 0, 0, 0);
        f32x4 a1 = __builtin_amdgcn_mfma_f32_16x16x32_f16(wA[1], bfrag, cq[1], 0, 0, 0);

        float xt1 = xs[((t + 1) & 511) * 17 + col];       // prefetch next x

        // serial critical path: prioritize this wave over the co-block's
        // slack-phase work (T5; drifted-phase regime)
        __builtin_amdgcn_s_setprio(1);

        // fused activations, hidden j0 (a0) and j0+1 (a1); rcps PAIRED
        float ei0 = __builtin_amdgcn_exp2f(-a0[0]);
        float ef0 = __builtin_amdgcn_exp2f(-a0[1]);
        float eg0 = __builtin_amdgcn_exp2f(-a0[2]);
        float eo0 = __builtin_amdgcn_exp2f(-a0[3]);
        float ei1 = __builtin_amdgcn_exp2f(-a1[0]);
        float ef1 = __builtin_amdgcn_exp2f(-a1[1]);
        float eg1 = __builtin_amdgcn_exp2f(-a1[2]);
        float eo1 = __builtin_amdgcn_exp2f(-a1[3]);
        float aI0 = 1.0f + ei0, aF0 = 1.0f + ef0, aG0 = 1.0f + eg0, aO0 = 1.0f + eo0;
        float aI1 = 1.0f + ei1, aF1 = 1.0f + ef1, aG1 = 1.0f + eg1, aO1 = 1.0f + eo1;
        float tIG0 = aI0 * aG0, tIG1 = aI1 * aG1;
        float num0 = fmaf(c0, tIG0, (1.0f - eg0) * aF0);
        float num1 = fmaf(c1, tIG1, (1.0f - eg1) * aF1);
        float D0 = aF0 * tIG0, D1 = aF1 * tIG1;
        float rD = __builtin_amdgcn_rcpf(D0 * D1);        // paired rcp #1
        c0 = num0 * (rD * D1);
        c1 = num1 * (rD * D0);
        float ec0 = __builtin_amdgcn_exp2f(c0 * (-2.0f * L2E));
        float ec1 = __builtin_amdgcn_exp2f(c1 * (-2.0f * L2E));
        float H0 = aO0 * (1.0f + ec0), H1 = aO1 * (1.0f + ec1);
        float rH = __builtin_amdgcn_rcpf(H0 * H1);        // paired rcp #2
        h0 = (1.0f - ec0) * (rH * H1);
        h1 = (1.0f - ec1) * (rH * H0);

        // adjacent hiddens -> one b32 write of the packed pair
        buf[wr] = __builtin_bit_cast(unsigned int, __builtin_amdgcn_cvt_pkrtz(h0, h1));

        __builtin_amdgcn_s_setprio(0);

        // next step's C-init in the pre-barrier slack
        #pragma unroll
        for (int tau = 0; tau < 2; ++tau)
            #pragma unroll
            for (int r = 0; r < 4; ++r)
                cq[tau][r] = fmaf(xt1, wih[tau][r], bia[tau][r]);

        __syncthreads();
        // B-frag: pairs quad*4..+3 of batch col = k quad*8..quad*8+7
        uint4 bv = *(const uint4*)&buf[col * 20 + quad * 4];
        bfrag = __builtin_bit_cast(f16x8, bv);
    }

    // ---- epilogue: out[b] = sum_j h_j * W_lin[j] + b_lin ----
    float v = fmaf(h0, wl0, h1 * wl1);
    v += __shfl_xor(v, 16);            // combine quads
    v += __shfl_xor(v, 32);
    if (lane < 16) ps[wv * 16 + col] = v;
    __syncthreads();
    if (tid < 16)
        out[base + tid] = b_lin[0] + ps[tid] + ps[16 + tid] + ps[32 + tid] + ps[48 + tid];
}

extern "C" void kernel_launch(void* const* d_in, const int* in_sizes, int n_in,
                              void* d_out, int out_size, void* d_ws, size_t ws_size,
                              hipStream_t stream) {
    const float* x     = (const float*)d_in[0];
    const float* W_ih  = (const float*)d_in[1];
    const float* W_hh  = (const float*)d_in[2];
    const float* b_ih  = (const float*)d_in[3];
    const float* b_hh  = (const float*)d_in[4];
    const float* W_lin = (const float*)d_in[5];
    const float* b_lin = (const float*)d_in[6];
    float* out = (float*)d_out;

    const int B = in_sizes[0] / 512;   // 8192
    dim3 grid(B / 16), block(256);
    lstm_ct4r<<<grid, block, 0, stream>>>(x, W_ih, W_hh, b_ih, b_hh, W_lin, b_lin, out);
}